// Round 8
// baseline (390.293 us; speedup 1.0000x reference)
//
#include <hip/hip_runtime.h>
#include <cstdint>

#define S_LEN 2048
#define EMB   2048
#define NHEAD 16
#define HDIM  128
#define NFUSE 2304   // fused proj width: 2048 q | 128 k | 128 v
#define LOG2E 1.4426950408889634f

typedef __attribute__((ext_vector_type(8))) _Float16 h8;
typedef __attribute__((ext_vector_type(4))) _Float16 h4;
typedef __attribute__((ext_vector_type(8))) short short8;
typedef __attribute__((ext_vector_type(4))) short short4v;
typedef __attribute__((ext_vector_type(4))) float f32x4;
typedef unsigned int u32;

// round-to-nearest-even float -> bf16 (finite inputs); used for the mask
__device__ inline short f2bf(float x) {
  union { float f; uint32_t u; } v; v.f = x;
  uint32_t r = v.u + 0x7fffu + ((v.u >> 16) & 1u);
  return (short)(r >> 16);
}
__device__ inline float bf2f(short b) {
  union { uint32_t u; float f; } v; v.u = ((uint32_t)(uint16_t)b) << 16;
  return v.f;
}
// raw v_exp_f32 (2^x); inputs are pre-scaled to log2 domain
__device__ inline float fexp2(float x) {
  float r;
  __asm__ volatile("v_exp_f32 %0, %1" : "=v"(r) : "v"(x));
  return r;
}
// pack 2 f32 -> 2 f16 (RTZ), result as u32
__device__ inline u32 pkrtz(float a, float b) {
  u32 r;
  __asm__ volatile("v_cvt_pkrtz_f16_f32 %0, %1, %2" : "=v"(r) : "v"(a), "v"(b));
  return r;
}
// async global->LDS, 16B per lane; lds base must be wave-uniform
__device__ inline void glds16(const void* g, void* l) {
  __builtin_amdgcn_global_load_lds(
      (const __attribute__((address_space(1))) u32*)g,
      (__attribute__((address_space(3))) u32*)l, 16, 0, 0);
}

// ---------------------------------------------------------------------------
// W1 group-reduce -> Wkv f32 [2048][256] (k cols 0..127, v cols 128..255)
// ---------------------------------------------------------------------------
__global__ __launch_bounds__(256) void reduce_w1_kernel(
    const float* __restrict__ W1, float* __restrict__ Wkv) {
  int idx = blockIdx.x * 256 + threadIdx.x;
  int i = idx >> 8;
  int c = idx & 255;
  int base = (c < 128) ? c : (c + 384);
  const float* r = W1 + (size_t)i * 1024 + base;
  Wkv[idx] = (r[0] + r[128]) + (r[256] + r[384]);
}

// ---------------------------------------------------------------------------
// elementwise f32 -> fp16; 4 elements/thread
// ---------------------------------------------------------------------------
__global__ __launch_bounds__(256) void cvt_x_kernel(
    const float* __restrict__ src, _Float16* __restrict__ dst) {
  size_t idx = (size_t)blockIdx.x * 256 + threadIdx.x;
  float4 v = *(const float4*)(src + idx * 4);
  h4 o;
  o[0] = (_Float16)v.x; o[1] = (_Float16)v.y;
  o[2] = (_Float16)v.z; o[3] = (_Float16)v.w;
  *(h4*)(dst + idx * 4) = o;
}

// ---------------------------------------------------------------------------
// mask f32 -> bf16 scaled by log2e (flash adds it to log2-domain logits)
// ---------------------------------------------------------------------------
__global__ __launch_bounds__(256) void cvt_mask_kernel(
    const float* __restrict__ src, short* __restrict__ dst) {
  size_t idx = (size_t)blockIdx.x * 256 + threadIdx.x;
  float4 v = *(const float4*)(src + idx * 4);
  short4v o;
  o[0] = f2bf(v.x * LOG2E); o[1] = f2bf(v.y * LOG2E);
  o[2] = f2bf(v.z * LOG2E); o[3] = f2bf(v.w * LOG2E);
  *(short4v*)(dst + idx * 4) = o;
}

// ---------------------------------------------------------------------------
// tiled transpose f32 W[K][N] -> fp16 T[N][K]; grid (N/64, K/64), 256 thr
// ---------------------------------------------------------------------------
__global__ __launch_bounds__(256) void transpose_f16_kernel(
    const float* __restrict__ W, _Float16* __restrict__ T, int K, int N) {
  __shared__ float Tt[64][65];
  const int tid = threadIdx.x;
  const int k0 = blockIdx.y * 64, n0 = blockIdx.x * 64;
  {
    int r = tid >> 2, c0 = (tid & 3) * 16;
    const float* src = W + (size_t)(k0 + r) * N + n0 + c0;
#pragma unroll
    for (int j = 0; j < 4; ++j) {
      float4 v = *(const float4*)(src + 4 * j);
      Tt[r][c0 + 4 * j + 0] = v.x; Tt[r][c0 + 4 * j + 1] = v.y;
      Tt[r][c0 + 4 * j + 2] = v.z; Tt[r][c0 + 4 * j + 3] = v.w;
    }
  }
  __syncthreads();
  {
    int n = tid >> 2, kc = (tid & 3) * 16;
    h8 o0, o1;
#pragma unroll
    for (int i = 0; i < 8; ++i) {
      o0[i] = (_Float16)Tt[kc + i][n];
      o1[i] = (_Float16)Tt[kc + 8 + i][n];
    }
    size_t off = (size_t)(n0 + n) * K + k0 + kc;
    *(h8*)(T + off) = o0;
    *(h8*)(T + off + 8) = o1;
  }
}

// ---------------------------------------------------------------------------
// fp16 MFMA GEMM: C[M][N] = A[M][K] @ B (Bt = B^T as [N][K] fp16).
// QSCALE: fp16 C out, cols < qlim scaled by log2e. else: f32 C out.
// 128x128 tile, BK=32, 4 waves; double-buffered LDS (2x16 KiB),
// global_load_lds staging, counted s_waitcnt vmcnt(4).
// ---------------------------------------------------------------------------
template <bool QSCALE>
__global__ __launch_bounds__(256, 3) void gemm_f16(
    const _Float16* __restrict__ A, const _Float16* __restrict__ Bt,
    float* __restrict__ C, _Float16* __restrict__ Cf,
    int M, int N, int K, int qlim) {
  extern __shared__ char smraw[];
  _Float16* sm = (_Float16*)smraw;
  const int BUFS = 8192;  // elements per buffer (A 4096 | B 4096)

  const int tid  = threadIdx.x;
  const int w    = tid >> 6;
  const int lane = tid & 63;
  const int quad = lane >> 4, col16 = lane & 15;
  const int row0 = blockIdx.y * 128, col0 = blockIdx.x * 128;
  const float esc = (col0 < qlim) ? LOG2E : 1.0f;

  const int srow  = w * 32 + (lane >> 2);
  const int kpart = (lane & 3) * 8;
  const _Float16* pA0 = A + (size_t)(row0 + srow) * K + kpart;
  const _Float16* pA1 = pA0 + (size_t)16 * K;
  const _Float16* pB0 = Bt + (size_t)(col0 + srow) * K + kpart;
  const _Float16* pB1 = pB0 + (size_t)16 * K;

  const int oA0 = (w * 32) * 32, oA1 = (w * 32 + 16) * 32;
  const int oB0 = 4096 + (w * 32) * 32, oB1 = 4096 + (w * 32 + 16) * 32;

#define STAGE_GEMM(bo)                                                        \
  do {                                                                        \
    glds16(pA0, sm + (bo) + oA0); glds16(pA1, sm + (bo) + oA1);               \
    glds16(pB0, sm + (bo) + oB0); glds16(pB1, sm + (bo) + oB1);               \
    pA0 += 32; pA1 += 32; pB0 += 32; pB1 += 32;                               \
  } while (0)

  f32x4 acc[2][8];
#pragma unroll
  for (int mt = 0; mt < 2; ++mt)
#pragma unroll
    for (int nt = 0; nt < 8; ++nt) {
      acc[mt][nt][0] = 0.f; acc[mt][nt][1] = 0.f;
      acc[mt][nt][2] = 0.f; acc[mt][nt][3] = 0.f;
    }

  const int nchunk = K >> 5;
  int bo = 0;
  STAGE_GEMM(0);

#pragma unroll 1
  for (int c = 0; c < nchunk; ++c) {
    if (c + 1 < nchunk) {
      STAGE_GEMM(bo ^ BUFS);
      __asm__ volatile("s_waitcnt vmcnt(4)" ::: "memory");
    } else {
      __asm__ volatile("s_waitcnt vmcnt(0)" ::: "memory");
    }
    __builtin_amdgcn_s_barrier();

    const _Float16* AS = sm + bo;
    const _Float16* BS = sm + bo + 4096;

    h8 af[2];
#pragma unroll
    for (int mt = 0; mt < 2; ++mt)
      af[mt] = *(const h8*)&AS[(w * 32 + mt * 16 + col16) * 32 + quad * 8];
#pragma unroll
    for (int nt = 0; nt < 8; ++nt) {
      h8 b8 = *(const h8*)&BS[(nt * 16 + col16) * 32 + quad * 8];
#pragma unroll
      for (int mt = 0; mt < 2; ++mt)
        acc[mt][nt] = __builtin_amdgcn_mfma_f32_16x16x32_f16(af[mt], b8, acc[mt][nt], 0, 0, 0);
    }
    __builtin_amdgcn_s_barrier();
    bo ^= BUFS;
  }
#undef STAGE_GEMM

#pragma unroll
  for (int mt = 0; mt < 2; ++mt)
#pragma unroll
    for (int nt = 0; nt < 8; ++nt)
#pragma unroll
      for (int r = 0; r < 4; ++r) {
        int row = row0 + w * 32 + mt * 16 + quad * 4 + r;
        int col = col0 + nt * 16 + col16;
        float v = acc[mt][nt][r];
        if constexpr (QSCALE) {
          Cf[(size_t)row * N + col] = (_Float16)(v * esc);
        } else {
          C[(size_t)row * N + col] = v;
        }
      }
}

// ---------------------------------------------------------------------------
// build VT fp16 [2][128][2048] from fused proj output cols 2176..2303 (v)
// grid 64 blocks x 256 thr; block = 64 s-rows  (bit-preserving short copies)
// ---------------------------------------------------------------------------
__global__ __launch_bounds__(256) void build_vt(
    const short* __restrict__ QKh, short* __restrict__ VT) {
  __shared__ short T[64][136];
  const int tid = threadIdx.x;
  const int gs = blockIdx.x * 64;
  const int b = gs >> 11;
  const int s = gs & 2047;
  {
    int r = tid >> 2, c0 = (tid & 3) * 32;
    const short* src = QKh + (size_t)(gs + r) * NFUSE + 2176 + c0;
#pragma unroll
    for (int j = 0; j < 4; ++j)
      *(short8*)&T[r][c0 + 8 * j] = *(const short8*)(src + 8 * j);
  }
  __syncthreads();
  {
    int d = tid >> 1, c = (tid & 1) * 32;
    short* dst = VT + (size_t)(b * HDIM + d) * S_LEN + s + c;
#pragma unroll
    for (int jo = 0; jo < 4; ++jo) {
      short8 o;
#pragma unroll
      for (int i = 0; i < 8; ++i) o[i] = T[c + jo * 8 + i][d];
      *(short8*)(dst + jo * 8) = o;
    }
  }
}

// ---------------------------------------------------------------------------
// fp16 MFMA flash attention, BM=64 (1 Q-tile/block, wave owns 16 q-rows),
// BN=64, swapped operands.
//  * Grid 1024 blocks (= 4/CU available; LDS 48 KiB -> 3/CU resident).
//    R7 lesson: 512-block grid capped occupancy at 2/CU regardless of LDS.
//  * R4 pipeline: all staging (K, V, mask) via glds16 one iter ahead;
//    queue/wave = [K4, M2, V4]; B1 waits vmcnt(4) (K+M ready, V flying);
//    mid-iter vmcnt(6) drains V only (next K+M stay in flight).
//  * LDS 48 KiB: K 16 | V 16 | P 8 | M 8.
//  * __launch_bounds__(256,2) (minimum promise; ~80 regs expected -> HW
//    can run 3 blocks/CU on its own; a (256,3) cap caused spill in R3/R6).
//  * defer-max (T13, THR=8 in log2 domain).
// grid (S/64, B*H), 256 threads = 4 waves.
// ---------------------------------------------------------------------------
__global__ __launch_bounds__(256, 2) void flash_f16(
    const _Float16* __restrict__ QKf, const _Float16* __restrict__ VT,
    const short* __restrict__ maskb, _Float16* __restrict__ AO) {
  __shared__ _Float16 KS[64 * 128];     // 16 KiB, [64 s][128 d] swizzled
  __shared__ _Float16 VtS[128 * 64];    // 16 KiB, [128 d][64 s] swizzled
  __shared__ _Float16 PsS[4 * 16 * 64]; //  8 KiB, [wave][16 q][64 s]
  __shared__ short    MkS[4 * 16 * 64]; //  8 KiB, [wave][16 q][64 s]

  const int tid   = threadIdx.x;
  const int w     = tid >> 6;
  const int lane  = tid & 63;
  const int quad  = lane >> 4;
  const int col16 = lane & 15;
  const int xq    = col16 & 7;
  const int bh = blockIdx.y, b = bh >> 4, h = bh & 15;
  const int t0 = blockIdx.x * 64;

  const int jr = lane >> 4;   // K/Q staging: row-within-instr 0..3
  const int kg = lane & 15;   // K/Q staging: dest granule (16B units)
  const int vr = lane >> 3;   // V/M staging: row-within-instr 0..7
  const int vg = lane & 7;    // V/M staging: dest granule

  _Float16* myK = KS + w * 2048;   // wave staging: 16 s-rows x 128
  _Float16* myV = VtS + w * 2048;  // wave staging: 32 d-rows x 64
  short*    myM = MkS + w * 1024;  // wave mask: 16 q-rows x 64
  _Float16* myP = PsS + w * 1024;  // wave P: 16 q-rows x 64

  // ---- Q prologue: stage wave's 16 q-rows, extract fragments
  h8 qf[4];
  {
#pragma unroll
    for (int j = 0; j < 4; ++j) {
      int rl = 4 * j + jr;
      int gq = kg ^ (rl & 7);
      size_t go = (size_t)(b * S_LEN + t0 + 16 * w + rl) * NFUSE
                + h * HDIM + gq * 8;
      glds16(QKf + go, myK + j * 512);
    }
    __asm__ volatile("s_waitcnt vmcnt(0)" ::: "memory");
#pragma unroll
    for (int c = 0; c < 4; ++c)
      qf[c] = *(const h8*)&myK[col16 * 128 + (((c * 4 + quad) ^ xq) * 8)];
    __asm__ volatile("s_waitcnt lgkmcnt(0)" ::: "memory");  // reads retired
  }

  // ---- per-lane staging offsets (source swizzled; LDS linear), 32-bit
  const _Float16* Kbase = QKf + (size_t)b * S_LEN * NFUSE + 2048;
  const _Float16* Vbase = VT + (size_t)b * HDIM * S_LEN;
  const short*    Mbase = maskb + (size_t)b * S_LEN * S_LEN;
  u32 offK[4], offV[4], offM[2];
#pragma unroll
  for (int j = 0; j < 4; ++j) {
    int rl = 4 * j + jr;
    offK[j] = (u32)(16 * w + rl) * NFUSE + (u32)((kg ^ (rl & 7)) * 8);
    int dl = 32 * w + 8 * j + vr;
    offV[j] = (u32)dl * S_LEN + (u32)((vg ^ (vr & 7)) * 8);
  }
#pragma unroll
  for (int j = 0; j < 2; ++j) {
    int mrw = j * 8 + vr;                       // 0..15 (wave-local q-row)
    int mq  = t0 + 16 * w + mrw;
    offM[j] = (u32)mq * S_LEN + (u32)((vg ^ (mrw & 7)) * 8);
  }

  // ---- issue K_0, M_0, V_0 (queue discipline: [K4, M2, V4])
#pragma unroll
  for (int j = 0; j < 4; ++j) glds16(Kbase + offK[j], myK + j * 512);
#pragma unroll
  for (int j = 0; j < 2; ++j) glds16(Mbase + offM[j], myM + j * 512);
#pragma unroll
  for (int j = 0; j < 4; ++j) glds16(Vbase + offV[j], myV + j * 512);
#pragma unroll
  for (int j = 0; j < 4; ++j) { offK[j] += 64 * NFUSE; offV[j] += 64; }
#pragma unroll
  for (int j = 0; j < 2; ++j) offM[j] += 64;

  f32x4 oacc[8];
#pragma unroll
  for (int d = 0; d < 8; ++d) {
    oacc[d][0] = 0.f; oacc[d][1] = 0.f;
    oacc[d][2] = 0.f; oacc[d][3] = 0.f;
  }
  float mrow = -3.0e38f, lrow = 0.f;

#pragma unroll 1
  for (int it = 0; it < S_LEN / 64; ++it) {
    // ---- B1: K_it + M_it arrived on all waves (V_it still in flight)
    __asm__ volatile("s_waitcnt vmcnt(4)" ::: "memory");
    __builtin_amdgcn_s_barrier();

    // mask -> regs (wave-local region; reads retire before B2)
    short4v msk[4];
#pragma unroll
    for (int nt = 0; nt < 4; ++nt)
      msk[nt] = *(const short4v*)
          &myM[col16 * 64 + (((quad + nt * 4) ^ (xq << 1)) << 2)];

    // ---- QK^T swapped: sacc[nt] = S^T (rows = s-local, cols = q)
    f32x4 sacc[4];
#pragma unroll
    for (int nt = 0; nt < 4; ++nt) {
      sacc[nt][0] = 0.f; sacc[nt][1] = 0.f;
      sacc[nt][2] = 0.f; sacc[nt][3] = 0.f;
    }
    __builtin_amdgcn_s_setprio(1);
#pragma unroll
    for (int c = 0; c < 4; ++c)
#pragma unroll
      for (int nt = 0; nt < 4; ++nt) {
        h8 k8 = *(const h8*)&KS[(nt * 16 + col16) * 128 + (((c * 4 + quad) ^ xq) * 8)];
        sacc[nt] = __builtin_amdgcn_mfma_f32_16x16x32_f16(k8, qf[c], sacc[nt], 0, 0, 0);
      }
    __builtin_amdgcn_s_setprio(0);

    // ---- B2: all waves' K/M LDS reads retired -> bufs free for prefetch
    __asm__ volatile("s_waitcnt lgkmcnt(0)" ::: "memory");
    __builtin_amdgcn_s_barrier();
    if (it + 1 < S_LEN / 64) {   // prefetch K,M_{it+1}; flies under SM+PV
#pragma unroll
      for (int j = 0; j < 4; ++j) glds16(Kbase + offK[j], myK + j * 512);
#pragma unroll
      for (int j = 0; j < 2; ++j) glds16(Mbase + offM[j], myM + j * 512);
#pragma unroll
      for (int j = 0; j < 4; ++j) offK[j] += 64 * NFUSE;
#pragma unroll
      for (int j = 0; j < 2; ++j) offM[j] += 64;
    }

    // ---- V_it drained (counted: K,M_{it+1} stay in flight)
    if (it + 1 < S_LEN / 64) {
      __asm__ volatile("s_waitcnt vmcnt(6)" ::: "memory");
    } else {
      __asm__ volatile("s_waitcnt vmcnt(0)" ::: "memory");
    }

    // ---- online softmax (base-2); lane owns Q-row col16
    {
      float vv[4][4];
#pragma unroll
      for (int nt = 0; nt < 4; ++nt)
#pragma unroll
        for (int r = 0; r < 4; ++r)
          vv[nt][r] = sacc[nt][r] + bf2f(msk[nt][r]);
      float mx = vv[0][0];
#pragma unroll
      for (int nt = 0; nt < 4; ++nt)
#pragma unroll
        for (int r = 0; r < 4; ++r) mx = fmaxf(mx, vv[nt][r]);
      mx = fmaxf(mx, __shfl_xor(mx, 16));
      mx = fmaxf(mx, __shfl_xor(mx, 32));

      float nm = fmaxf(mrow, mx);
      if (__all(mx - mrow <= 8.0f)) {
        nm = mrow;                          // defer: P bounded by 2^8
      } else {
        float al = fexp2(mrow - nm);
        lrow *= al;
#pragma unroll
        for (int d = 0; d < 8; ++d) {
          oacc[d][0] *= al; oacc[d][1] *= al;
          oacc[d][2] *= al; oacc[d][3] *= al;
        }
        mrow = nm;
      }

      float ps = 0.f;
      u32 pk0[4], pk1[4];
#pragma unroll
      for (int nt = 0; nt < 4; ++nt) {
        float p0 = fexp2(vv[nt][0] - nm);
        float p1 = fexp2(vv[nt][1] - nm);
        float p2 = fexp2(vv[nt][2] - nm);
        float p3 = fexp2(vv[nt][3] - nm);
        ps += (p0 + p1) + (p2 + p3);
        pk0[nt] = pkrtz(p0, p1);
        pk1[nt] = pkrtz(p2, p3);
      }
      ps += __shfl_xor(ps, 16);
      ps += __shfl_xor(ps, 32);
      lrow += ps;

      // P store: 4x b64, granule-XOR swizzled (wave-local region)
      int pbase = col16 * 64 + (quad & 1) * 4;
#pragma unroll
      for (int nt = 0; nt < 4; ++nt) {
        uint2 pv2; pv2.x = pk0[nt]; pv2.y = pk1[nt];
        *(uint2*)&myP[pbase + (((2 * nt + (quad >> 1)) ^ xq) * 8)] = pv2;
      }
    }

    // ---- PV swapped: oacc[d] += mfma(V^T-frag, P^T-frag)
    __asm__ volatile("s_waitcnt lgkmcnt(0)" ::: "memory");  // P visible in-wave
    h8 pa0 = *(const h8*)&myP[col16 * 64 + ((quad ^ xq) * 8)];
    h8 pa1 = *(const h8*)&myP[col16 * 64 + (((4 + quad) ^ xq) * 8)];
    __builtin_amdgcn_s_setprio(1);
#pragma unroll
    for (int d = 0; d < 8; ++d) {
      int vo = (d * 16 + col16) * 64;
      h8 vb0 = *(const h8*)&VtS[vo + ((quad ^ xq) * 8)];
      h8 vb1 = *(const h8*)&VtS[vo + (((4 + quad) ^ xq) * 8)];
      oacc[d] = __builtin_amdgcn_mfma_f32_16x16x32_f16(vb0, pa0, oacc[d], 0, 0, 0);
      oacc[d] = __builtin_amdgcn_mfma_f32_16x16x32_f16(vb1, pa1, oacc[d], 0, 0, 0);
    }
    __builtin_amdgcn_s_setprio(0);

    // ---- B3: all waves' VtS reads retired -> V buf free for prefetch
    __asm__ volatile("s_waitcnt lgkmcnt(0)" ::: "memory");
    __builtin_amdgcn_s_barrier();
    if (it + 1 < S_LEN / 64) {
#pragma unroll
      for (int j = 0; j < 4; ++j) glds16(Vbase + offV[j], myV + j * 512);
#pragma unroll
      for (int j = 0; j < 4; ++j) offV[j] += 64;
    }
  }

  // ---- epilogue: normalize, packed 8B stores, AO fp16 [4096][2048]
  {
    float inv = 1.0f / lrow;
    int q = t0 + 16 * w + col16;
    _Float16* dst = AO + (size_t)(b * S_LEN + q) * EMB + h * HDIM + quad * 4;
#pragma unroll
    for (int d = 0; d < 8; ++d) {
      h4 o4;
#pragma unroll
      for (int r = 0; r < 4; ++r) o4[r] = (_Float16)(oacc[d][r] * inv);
      *(h4*)(dst + d * 16) = o4;
    }
  }
}

// ---------------------------------------------------------------------------
extern "C" void kernel_launch(void* const* d_in, const int* in_sizes, int n_in,
                              void* d_out, int out_size, void* d_ws, size_t ws_size,
                              hipStream_t stream) {
  const float* x    = (const float*)d_in[0];
  const float* mask = (const float*)d_in[1];
  const float* W1   = (const float*)d_in[2];
  const float* W2   = (const float*)d_in[3];
  const float* W3   = (const float*)d_in[4];
  float* out = (float*)d_out;

  char* ws = (char*)d_ws;
  size_t off = 0;
  _Float16* xf   = (_Float16*)(ws + off); off += (size_t)4096 * 2048 * 2;    // 16 MiB
  _Float16* Wtf  = (_Float16*)(ws + off); off += (size_t)NFUSE * 2048 * 2;   //  9 MiB
  _Float16* QKf  = (_Float16*)(ws + off); off += (size_t)4096 * NFUSE * 2;   // 18 MiB
  _Float16* VT   = (_Float16*)(ws + off); off += (size_t)2 * 128 * 2048 * 2; //  1 MiB
  _Float16* AOf  = (_Float16*)(ws + off); off += (size_t)4096 * 2048 * 2;    // 16 MiB
  float*    Wkv  = (float*)(ws + off);    off += (size_t)2048 * 256 * 4;     //  2 MiB
  short*    maskb= (short*)(ws + off);    off += (size_t)2 * 2048 * 2048 * 2;// 16 MiB
  _Float16* W3t  = xf;  // alias: xf dead after fused GEMM; W3 transpose runs after

  // 1) prep: Wkv reduce, x->fp16, mask->bf16*log2e, fused W^T fp16
  reduce_w1_kernel<<<2048, 256, 0, stream>>>(W1, Wkv);
  cvt_x_kernel<<<8192, 256, 0, stream>>>(x, xf);
  cvt_mask_kernel<<<8192, 256, 0, stream>>>(mask, maskb);
  transpose_f16_kernel<<<dim3(32, 32), 256, 0, stream>>>(W2, Wtf, 2048, 2048);
  transpose_f16_kernel<<<dim3(4, 32), 256, 0, stream>>>(
      Wkv, Wtf + (size_t)2048 * 2048, 2048, 256);

  // 2) fused projection GEMM: [4096][2304] = x @ [W2 | Wk | Wv], fp16 out,
  //    Q cols pre-scaled by log2e
  gemm_f16<true><<<dim3(NFUSE / 128, 32), 256, 32768, stream>>>(
      xf, Wtf, nullptr, QKf, 4096, NFUSE, 2048, 2048);

  // 3) V^T extraction
  build_vt<<<64, 256, 0, stream>>>((const short*)QKf, (short*)VT);

  // 4) attention (BM=64: 1024 blocks)
  flash_f16<<<dim3(S_LEN / 64, 2 * NHEAD), 256, 0, stream>>>(
      QKf, VT, maskb, AOf);

  // 5) output projection (fp16 in, f32 out)
  transpose_f16_kernel<<<dim3(32, 32), 256, 0, stream>>>(W3, W3t, 2048, 2048);
  gemm_f16<false><<<dim3(16, 32), 256, 32768, stream>>>(
      AOf, W3t, out, nullptr, 4096, 2048, 2048, 0);
}

// Round 9
// 346.474 us; speedup vs baseline: 1.1265x; 1.1265x over previous
//
#include <hip/hip_runtime.h>
#include <cstdint>

#define S_LEN 2048
#define EMB   2048
#define NHEAD 16
#define HDIM  128
#define NFUSE 2304   // fused proj width: 2048 q | 128 k | 128 v
#define LOG2E 1.4426950408889634f

typedef __attribute__((ext_vector_type(8))) _Float16 h8;
typedef __attribute__((ext_vector_type(4))) _Float16 h4;
typedef __attribute__((ext_vector_type(8))) short short8;
typedef __attribute__((ext_vector_type(4))) short short4v;
typedef __attribute__((ext_vector_type(4))) float f32x4;
typedef unsigned int u32;

// round-to-nearest-even float -> bf16 (finite inputs); used for the mask
__device__ inline short f2bf(float x) {
  union { float f; uint32_t u; } v; v.f = x;
  uint32_t r = v.u + 0x7fffu + ((v.u >> 16) & 1u);
  return (short)(r >> 16);
}
__device__ inline float bf2f(short b) {
  union { uint32_t u; float f; } v; v.u = ((uint32_t)(uint16_t)b) << 16;
  return v.f;
}
// raw v_exp_f32 (2^x); inputs are pre-scaled to log2 domain
__device__ inline float fexp2(float x) {
  float r;
  __asm__ volatile("v_exp_f32 %0, %1" : "=v"(r) : "v"(x));
  return r;
}
// pack 2 f32 -> 2 f16 (RTZ), result as u32
__device__ inline u32 pkrtz(float a, float b) {
  u32 r;
  __asm__ volatile("v_cvt_pkrtz_f16_f32 %0, %1, %2" : "=v"(r) : "v"(a), "v"(b));
  return r;
}
// async global->LDS, 16B per lane; lds base must be wave-uniform
__device__ inline void glds16(const void* g, void* l) {
  __builtin_amdgcn_global_load_lds(
      (const __attribute__((address_space(1))) u32*)g,
      (__attribute__((address_space(3))) u32*)l, 16, 0, 0);
}

// ---------------------------------------------------------------------------
// fused elementwise prep: blocks [0,8192) cvt x f32->fp16;
// blocks [8192,16384) cvt mask f32->bf16*log2e. 1024 elems/block.
// ---------------------------------------------------------------------------
__global__ __launch_bounds__(256) void cvt_xm_kernel(
    const float* __restrict__ x, _Float16* __restrict__ xf,
    const float* __restrict__ mask, short* __restrict__ maskb) {
  int bid = blockIdx.x;
  if (bid < 8192) {
    size_t idx = (size_t)bid * 256 + threadIdx.x;
    float4 v = *(const float4*)(x + idx * 4);
    h4 o;
    o[0] = (_Float16)v.x; o[1] = (_Float16)v.y;
    o[2] = (_Float16)v.z; o[3] = (_Float16)v.w;
    *(h4*)(xf + idx * 4) = o;
  } else {
    size_t idx = (size_t)(bid - 8192) * 256 + threadIdx.x;
    float4 v = *(const float4*)(mask + idx * 4);
    short4v o;
    o[0] = f2bf(v.x * LOG2E); o[1] = f2bf(v.y * LOG2E);
    o[2] = f2bf(v.z * LOG2E); o[3] = f2bf(v.w * LOG2E);
    *(short4v*)(maskb + idx * 4) = o;
  }
}

// ---------------------------------------------------------------------------
// tiled transpose f32 W[K][N] -> fp16 T[N][K]; grid (N/64, K/64), 256 thr
// ---------------------------------------------------------------------------
__global__ __launch_bounds__(256) void transpose_f16_kernel(
    const float* __restrict__ W, _Float16* __restrict__ T, int K, int N) {
  __shared__ float Tt[64][65];
  const int tid = threadIdx.x;
  const int k0 = blockIdx.y * 64, n0 = blockIdx.x * 64;
  {
    int r = tid >> 2, c0 = (tid & 3) * 16;
    const float* src = W + (size_t)(k0 + r) * N + n0 + c0;
#pragma unroll
    for (int j = 0; j < 4; ++j) {
      float4 v = *(const float4*)(src + 4 * j);
      Tt[r][c0 + 4 * j + 0] = v.x; Tt[r][c0 + 4 * j + 1] = v.y;
      Tt[r][c0 + 4 * j + 2] = v.z; Tt[r][c0 + 4 * j + 3] = v.w;
    }
  }
  __syncthreads();
  {
    int n = tid >> 2, kc = (tid & 3) * 16;
    h8 o0, o1;
#pragma unroll
    for (int i = 0; i < 8; ++i) {
      o0[i] = (_Float16)Tt[kc + i][n];
      o1[i] = (_Float16)Tt[kc + 8 + i][n];
    }
    size_t off = (size_t)(n0 + n) * K + k0 + kc;
    *(h8*)(T + off) = o0;
    *(h8*)(T + off + 8) = o1;
  }
}

// ---------------------------------------------------------------------------
// fused W1 group-reduce + transpose -> fp16 T rows [0,256) x K=2048
// (replaces reduce_w1 + transpose; T points at Wtf + 2048*2048).
// Wkv[k][c] = sum_j W1[k][base(c) + 128 j], base(c) = c<128 ? c : c+384.
// grid (4, 32), 256 thr. Each block's n-range lies entirely on one side.
// ---------------------------------------------------------------------------
__global__ __launch_bounds__(256) void transpose_wkv_kernel(
    const float* __restrict__ W1, _Float16* __restrict__ T) {
  __shared__ float Tt[64][65];
  const int tid = threadIdx.x;
  const int k0 = blockIdx.y * 64, n0 = blockIdx.x * 64;
  {
    int r = tid >> 2, c0 = (tid & 3) * 16;
    int base = n0 + c0 + ((n0 >= 128) ? 384 : 0);
    const float* src = W1 + (size_t)(k0 + r) * 1024 + base;
#pragma unroll
    for (int j = 0; j < 4; ++j) {
      float4 s0 = *(const float4*)(src + 4 * j);
      float4 s1 = *(const float4*)(src + 128 + 4 * j);
      float4 s2 = *(const float4*)(src + 256 + 4 * j);
      float4 s3 = *(const float4*)(src + 384 + 4 * j);
      Tt[r][c0 + 4 * j + 0] = (s0.x + s1.x) + (s2.x + s3.x);
      Tt[r][c0 + 4 * j + 1] = (s0.y + s1.y) + (s2.y + s3.y);
      Tt[r][c0 + 4 * j + 2] = (s0.z + s1.z) + (s2.z + s3.z);
      Tt[r][c0 + 4 * j + 3] = (s0.w + s1.w) + (s2.w + s3.w);
    }
  }
  __syncthreads();
  {
    int n = tid >> 2, kc = (tid & 3) * 16;
    h8 o0, o1;
#pragma unroll
    for (int i = 0; i < 8; ++i) {
      o0[i] = (_Float16)Tt[kc + i][n];
      o1[i] = (_Float16)Tt[kc + 8 + i][n];
    }
    size_t off = (size_t)(n0 + n) * 2048 + k0 + kc;
    *(h8*)(T + off) = o0;
    *(h8*)(T + off + 8) = o1;
  }
}

// ---------------------------------------------------------------------------
// fp16 MFMA GEMM: C[M][N] = A[M][K] @ B (Bt = B^T as [N][K] fp16).
// QSCALE: fp16 C out, cols < qlim scaled by log2e. else: f32 C out.
// 128x128 tile, BK=32, 4 waves; double-buffered LDS (2x16 KiB),
// global_load_lds staging, counted s_waitcnt vmcnt(4).
// XCD-chunked block swizzle (T1): grid size must be a multiple of 8 --
// each XCD gets a contiguous band of tiles -> A-panel reuse hits its L2.
// ---------------------------------------------------------------------------
template <bool QSCALE>
__global__ __launch_bounds__(256, 3) void gemm_f16(
    const _Float16* __restrict__ A, const _Float16* __restrict__ Bt,
    float* __restrict__ C, _Float16* __restrict__ Cf,
    int M, int N, int K, int qlim) {
  extern __shared__ char smraw[];
  _Float16* sm = (_Float16*)smraw;
  const int BUFS = 8192;  // elements per buffer (A 4096 | B 4096)

  const int tid  = threadIdx.x;
  const int w    = tid >> 6;
  const int lane = tid & 63;
  const int quad = lane >> 4, col16 = lane & 15;

  // XCD swizzle: id%8 (the XCD this wg lands on) picks a contiguous chunk
  const int nwgx = gridDim.x;
  const int id   = blockIdx.y * nwgx + blockIdx.x;
  const int cpx  = (nwgx * gridDim.y) >> 3;
  const int sid  = (id & 7) * cpx + (id >> 3);
  const int bx   = sid % nwgx, by = sid / nwgx;

  const int row0 = by * 128, col0 = bx * 128;
  const float esc = (col0 < qlim) ? LOG2E : 1.0f;

  const int srow  = w * 32 + (lane >> 2);
  const int kpart = (lane & 3) * 8;
  const _Float16* pA0 = A + (size_t)(row0 + srow) * K + kpart;
  const _Float16* pA1 = pA0 + (size_t)16 * K;
  const _Float16* pB0 = Bt + (size_t)(col0 + srow) * K + kpart;
  const _Float16* pB1 = pB0 + (size_t)16 * K;

  const int oA0 = (w * 32) * 32, oA1 = (w * 32 + 16) * 32;
  const int oB0 = 4096 + (w * 32) * 32, oB1 = 4096 + (w * 32 + 16) * 32;

#define STAGE_GEMM(bo)                                                        \
  do {                                                                        \
    glds16(pA0, sm + (bo) + oA0); glds16(pA1, sm + (bo) + oA1);               \
    glds16(pB0, sm + (bo) + oB0); glds16(pB1, sm + (bo) + oB1);               \
    pA0 += 32; pA1 += 32; pB0 += 32; pB1 += 32;                               \
  } while (0)

  f32x4 acc[2][8];
#pragma unroll
  for (int mt = 0; mt < 2; ++mt)
#pragma unroll
    for (int nt = 0; nt < 8; ++nt) {
      acc[mt][nt][0] = 0.f; acc[mt][nt][1] = 0.f;
      acc[mt][nt][2] = 0.f; acc[mt][nt][3] = 0.f;
    }

  const int nchunk = K >> 5;
  int bo = 0;
  STAGE_GEMM(0);

#pragma unroll 1
  for (int c = 0; c < nchunk; ++c) {
    if (c + 1 < nchunk) {
      STAGE_GEMM(bo ^ BUFS);
      __asm__ volatile("s_waitcnt vmcnt(4)" ::: "memory");
    } else {
      __asm__ volatile("s_waitcnt vmcnt(0)" ::: "memory");
    }
    __builtin_amdgcn_s_barrier();

    const _Float16* AS = sm + bo;
    const _Float16* BS = sm + bo + 4096;

    h8 af[2];
#pragma unroll
    for (int mt = 0; mt < 2; ++mt)
      af[mt] = *(const h8*)&AS[(w * 32 + mt * 16 + col16) * 32 + quad * 8];
#pragma unroll
    for (int nt = 0; nt < 8; ++nt) {
      h8 b8 = *(const h8*)&BS[(nt * 16 + col16) * 32 + quad * 8];
#pragma unroll
      for (int mt = 0; mt < 2; ++mt)
        acc[mt][nt] = __builtin_amdgcn_mfma_f32_16x16x32_f16(af[mt], b8, acc[mt][nt], 0, 0, 0);
    }
    __builtin_amdgcn_s_barrier();
    bo ^= BUFS;
  }
#undef STAGE_GEMM

#pragma unroll
  for (int mt = 0; mt < 2; ++mt)
#pragma unroll
    for (int nt = 0; nt < 8; ++nt)
#pragma unroll
      for (int r = 0; r < 4; ++r) {
        int row = row0 + w * 32 + mt * 16 + quad * 4 + r;
        int col = col0 + nt * 16 + col16;
        float v = acc[mt][nt][r];
        if constexpr (QSCALE) {
          Cf[(size_t)row * N + col] = (_Float16)(v * esc);
        } else {
          C[(size_t)row * N + col] = v;
        }
      }
}

// ---------------------------------------------------------------------------
// build VT fp16 [2][128][2048] from fused proj output cols 2176..2303 (v)
// grid 64 blocks x 256 thr; block = 64 s-rows  (bit-preserving short copies)
// ---------------------------------------------------------------------------
__global__ __launch_bounds__(256) void build_vt(
    const short* __restrict__ QKh, short* __restrict__ VT) {
  __shared__ short T[64][136];
  const int tid = threadIdx.x;
  const int gs = blockIdx.x * 64;
  const int b = gs >> 11;
  const int s = gs & 2047;
  {
    int r = tid >> 2, c0 = (tid & 3) * 32;
    const short* src = QKh + (size_t)(gs + r) * NFUSE + 2176 + c0;
#pragma unroll
    for (int j = 0; j < 4; ++j)
      *(short8*)&T[r][c0 + 8 * j] = *(const short8*)(src + 8 * j);
  }
  __syncthreads();
  {
    int d = tid >> 1, c = (tid & 1) * 32;
    short* dst = VT + (size_t)(b * HDIM + d) * S_LEN + s + c;
#pragma unroll
    for (int jo = 0; jo < 4; ++jo) {
      short8 o;
#pragma unroll
      for (int i = 0; i < 8; ++i) o[i] = T[c + jo * 8 + i][d];
      *(short8*)(dst + jo * 8) = o;
    }
  }
}

// ---------------------------------------------------------------------------
// fp16 MFMA flash attention, BM=128 (2 Q-tiles/wave), BN=64, swapped operands.
// == the R4 kernel verbatim (measured 113.6 us) ==
//  * single-pass fp16 QK^T; mask pre-converted to bf16*log2e.
//  * mask staged per-WAVE into private LDS via 4 coalesced glds16/iter
//    (XOR-swizzled source, swizzled ds_read_b64 readback) -- no barriers.
//  * LDS 64 KiB (K 16 | V 16 | P 16 | M 16) -> 2 blocks/CU (grid=512 caps
//    occupancy at 2/CU anyway; R7/R8 showed smaller-LDS variants regress).
//  * launch_bounds (256,2): ~100 regs, no spill ((256,3) spills: R3/R6).
//  * defer-max (T13, THR=8 in log2 domain).
//  * pipeline: queue/wave = [K4, M4, V4]; B1 waits vmcnt(8) (K arrived);
//    post-QK vmcnt(0) (M+V arrived); K+M prefetch after B2, V after B3.
// grid (S/128, B*H), 256 threads = 4 waves.
// ---------------------------------------------------------------------------
__global__ __launch_bounds__(256, 2) void flash_f16(
    const _Float16* __restrict__ QKf, const _Float16* __restrict__ VT,
    const short* __restrict__ maskb, _Float16* __restrict__ AO) {
  __shared__ _Float16 KS[64 * 128];        // 16 KiB, [64 s][128 d] swizzled
  __shared__ _Float16 VtS[128 * 64];       // 16 KiB, [128 d][64 s] swizzled
  __shared__ _Float16 PsS[2 * 4 * 16 * 64];// 16 KiB, [tile][wave][16 q][64 s]
  __shared__ short    MkS[4 * 32 * 64];    // 16 KiB, [wave][32 q-rows][64 s]

  const int tid   = threadIdx.x;
  const int w     = tid >> 6;
  const int lane  = tid & 63;
  const int quad  = lane >> 4;
  const int col16 = lane & 15;
  const int xq    = col16 & 7;
  const int bh = blockIdx.y, b = bh >> 4, h = bh & 15;
  const int t0 = blockIdx.x * 128;

  const int jr = lane >> 4;   // K/Q staging: row-within-instr 0..3
  const int kg = lane & 15;   // K/Q staging: dest granule (16B units)
  const int vr = lane >> 3;   // V staging: row-within-instr 0..7
  const int vg = lane & 7;    // V staging: dest granule

  _Float16* myK = KS + w * 2048;   // wave staging region: 16 rows x 128
  _Float16* myV = VtS + w * 2048;  // wave staging region: 32 d-rows x 64
  short*    myM = MkS + w * 2048;  // wave mask region: 32 q-rows x 64

  // ---- Q prologue: wave-local glds staging + fragment extraction
  h8 qf[2][4];
#pragma unroll
  for (int t = 0; t < 2; ++t) {
#pragma unroll
    for (int j = 0; j < 4; ++j) {
      int rl = 4 * j + jr;
      int gq = kg ^ (rl & 7);
      size_t go = (size_t)(b * S_LEN + t0 + 64 * t + 16 * w + rl) * NFUSE
                + h * HDIM + gq * 8;
      glds16(QKf + go, myK + j * 512);
    }
    __asm__ volatile("s_waitcnt vmcnt(0)" ::: "memory");
#pragma unroll
    for (int c = 0; c < 4; ++c)
      qf[t][c] = *(const h8*)&myK[col16 * 128 + (((c * 4 + quad) ^ xq) * 8)];
    __asm__ volatile("s_waitcnt lgkmcnt(0)" ::: "memory");  // reads retired
  }

  // ---- per-lane staging offsets (source swizzled; LDS linear), 32-bit
  const _Float16* Kbase = QKf + (size_t)b * S_LEN * NFUSE + 2048;
  const _Float16* Vbase = VT + (size_t)b * HDIM * S_LEN;
  const short*    Mbase = maskb + (size_t)b * S_LEN * S_LEN;
  u32 offK[4], offV[4], offM[4];
#pragma unroll
  for (int j = 0; j < 4; ++j) {
    int rl = 4 * j + jr;
    offK[j] = (u32)(16 * w + rl) * NFUSE + (u32)((kg ^ (rl & 7)) * 8);
    int dl = 32 * w + 8 * j + vr;
    offV[j] = (u32)dl * S_LEN + (u32)((vg ^ (vr & 7)) * 8);
    int mrw = j * 8 + (lane >> 3);                 // 0..31
    int mq  = t0 + 64 * (mrw >> 4) + 16 * w + (mrw & 15);
    offM[j] = (u32)mq * S_LEN + (u32)(((lane & 7) ^ (mrw & 7)) * 8);
  }

  // ---- issue K_0, M_0, V_0 (queue discipline: [K4, M4, V4])
#pragma unroll
  for (int j = 0; j < 4; ++j) glds16(Kbase + offK[j], myK + j * 512);
#pragma unroll
  for (int j = 0; j < 4; ++j) glds16(Mbase + offM[j], myM + j * 512);
#pragma unroll
  for (int j = 0; j < 4; ++j) glds16(Vbase + offV[j], myV + j * 512);
#pragma unroll
  for (int j = 0; j < 4; ++j) {
    offK[j] += 64 * NFUSE; offM[j] += 64; offV[j] += 64;
  }

  f32x4 oacc[2][8];
#pragma unroll
  for (int t = 0; t < 2; ++t)
#pragma unroll
    for (int d = 0; d < 8; ++d) {
      oacc[t][d][0] = 0.f; oacc[t][d][1] = 0.f;
      oacc[t][d][2] = 0.f; oacc[t][d][3] = 0.f;
    }
  float mrow[2] = {-3.0e38f, -3.0e38f};
  float lrow[2] = {0.f, 0.f};

#pragma unroll 1
  for (int it = 0; it < S_LEN / 64; ++it) {
    // ---- B1: K_it arrived on all waves (M_it, V_it still in flight)
    __asm__ volatile("s_waitcnt vmcnt(8)" ::: "memory");
    __builtin_amdgcn_s_barrier();

    // ---- QK^T swapped: sacc[t][nt] = S^T (rows = s-local, cols = q)
    f32x4 sacc[2][4];
#pragma unroll
    for (int t = 0; t < 2; ++t)
#pragma unroll
      for (int nt = 0; nt < 4; ++nt) {
        sacc[t][nt][0] = 0.f; sacc[t][nt][1] = 0.f;
        sacc[t][nt][2] = 0.f; sacc[t][nt][3] = 0.f;
      }
    __builtin_amdgcn_s_setprio(1);
#pragma unroll
    for (int c = 0; c < 4; ++c)
#pragma unroll
      for (int nt = 0; nt < 4; ++nt) {
        h8 k8 = *(const h8*)&KS[(nt * 16 + col16) * 128 + (((c * 4 + quad) ^ xq) * 8)];
#pragma unroll
        for (int t = 0; t < 2; ++t)
          sacc[t][nt] = __builtin_amdgcn_mfma_f32_16x16x32_f16(k8, qf[t][c], sacc[t][nt], 0, 0, 0);
      }
    __builtin_amdgcn_s_setprio(0);

    // ---- M_it + V_it drained; read mask regs (wave-local) before barrier
    __asm__ volatile("s_waitcnt vmcnt(0)" ::: "memory");
    short4v msk[2][4];
#pragma unroll
    for (int t = 0; t < 2; ++t)
#pragma unroll
      for (int nt = 0; nt < 4; ++nt)
        msk[t][nt] = *(const short4v*)
            &myM[(t * 16 + col16) * 64 + (((quad + nt * 4) ^ (xq << 1)) << 2)];
    __asm__ volatile("s_waitcnt lgkmcnt(0)" ::: "memory");  // reads retired
    // ---- B2: K-buf free on all waves
    __builtin_amdgcn_s_barrier();

    if (it + 1 < S_LEN / 64) {   // prefetch K,M_{it+1}, flies under softmax+PV
#pragma unroll
      for (int j = 0; j < 4; ++j) glds16(Kbase + offK[j], myK + j * 512);
#pragma unroll
      for (int j = 0; j < 4; ++j) glds16(Mbase + offM[j], myM + j * 512);
#pragma unroll
      for (int j = 0; j < 4; ++j) { offK[j] += 64 * NFUSE; offM[j] += 64; }
    }

    // ---- online softmax (base-2), per tile; lane owns Q-row col16
#pragma unroll
    for (int t = 0; t < 2; ++t) {
      float vv[4][4];
#pragma unroll
      for (int nt = 0; nt < 4; ++nt)
#pragma unroll
        for (int r = 0; r < 4; ++r)
          vv[nt][r] = sacc[t][nt][r] + bf2f(msk[t][nt][r]);
      float mx = vv[0][0];
#pragma unroll
      for (int nt = 0; nt < 4; ++nt)
#pragma unroll
        for (int r = 0; r < 4; ++r) mx = fmaxf(mx, vv[nt][r]);
      mx = fmaxf(mx, __shfl_xor(mx, 16));
      mx = fmaxf(mx, __shfl_xor(mx, 32));

      float nm = fmaxf(mrow[t], mx);
      if (__all(mx - mrow[t] <= 8.0f)) {
        nm = mrow[t];                       // defer: P bounded by 2^8
      } else {
        float al = fexp2(mrow[t] - nm);
        lrow[t] *= al;
#pragma unroll
        for (int d = 0; d < 8; ++d) {
          oacc[t][d][0] *= al; oacc[t][d][1] *= al;
          oacc[t][d][2] *= al; oacc[t][d][3] *= al;
        }
        mrow[t] = nm;
      }

      float ps = 0.f;
      u32 pk0[4], pk1[4];
#pragma unroll
      for (int nt = 0; nt < 4; ++nt) {
        float p0 = fexp2(vv[nt][0] - nm);
        float p1 = fexp2(vv[nt][1] - nm);
        float p2 = fexp2(vv[nt][2] - nm);
        float p3 = fexp2(vv[nt][3] - nm);
        ps += (p0 + p1) + (p2 + p3);
        pk0[nt] = pkrtz(p0, p1);
        pk1[nt] = pkrtz(p2, p3);
      }
      ps += __shfl_xor(ps, 16);
      ps += __shfl_xor(ps, 32);
      lrow[t] += ps;

      // P store: 4x b64, granule-XOR swizzled
      int pbase = ((t * 4 + w) * 16 + col16) * 64 + (quad & 1) * 4;
#pragma unroll
      for (int nt = 0; nt < 4; ++nt) {
        uint2 pv2; pv2.x = pk0[nt]; pv2.y = pk1[nt];
        *(uint2*)&PsS[pbase + (((2 * nt + (quad >> 1)) ^ xq) * 8)] = pv2;
      }
    }

    // ---- PV swapped: oacc[t][d] += mfma(V^T-frag, P^T-frag)
    __asm__ volatile("s_waitcnt lgkmcnt(0)" ::: "memory");  // P visible in-wave
    h8 pa[2][2];
#pragma unroll
    for (int t = 0; t < 2; ++t) {
      int pb = ((t * 4 + w) * 16 + col16) * 64;
      pa[t][0] = *(const h8*)&PsS[pb + ((quad ^ xq) * 8)];
      pa[t][1] = *(const h8*)&PsS[pb + (((4 + quad) ^ xq) * 8)];
    }
    __builtin_amdgcn_s_setprio(1);
#pragma unroll
    for (int d = 0; d < 8; ++d) {
      int vo = (d * 16 + col16) * 64;
      h8 vb0 = *(const h8*)&VtS[vo + ((quad ^ xq) * 8)];
      h8 vb1 = *(const h8*)&VtS[vo + (((4 + quad) ^ xq) * 8)];
#pragma unroll
      for (int t = 0; t < 2; ++t) {
        oacc[t][d] = __builtin_amdgcn_mfma_f32_16x16x32_f16(vb0, pa[t][0], oacc[t][d], 0, 0, 0);
        oacc[t][d] = __builtin_amdgcn_mfma_f32_16x16x32_f16(vb1, pa[t][1], oacc[t][d], 0, 0, 0);
      }
    }
    __builtin_amdgcn_s_setprio(0);

    // ---- B3: V-buf free on all waves; prefetch V_{it+1}
    __builtin_amdgcn_s_barrier();
    if (it + 1 < S_LEN / 64) {
#pragma unroll
      for (int j = 0; j < 4; ++j) glds16(Vbase + offV[j], myV + j * 512);
#pragma unroll
      for (int j = 0; j < 4; ++j) offV[j] += 64;
    }
  }

  // ---- epilogue: normalize, packed 8B stores, AO fp16 [4096][2048]
#pragma unroll
  for (int t = 0; t < 2; ++t) {
    float inv = 1.0f / lrow[t];
    int q = t0 + 64 * t + 16 * w + col16;
    _Float16* dst = AO + (size_t)(b * S_LEN + q) * EMB + h * HDIM + quad * 4;
#pragma unroll
    for (int d = 0; d < 8; ++d) {
      h4 o4;
#pragma unroll
      for (int r = 0; r < 4; ++r) o4[r] = (_Float16)(oacc[t][d][r] * inv);
      *(h4*)(dst + d * 16) = o4;
    }
  }
}

// ---------------------------------------------------------------------------
extern "C" void kernel_launch(void* const* d_in, const int* in_sizes, int n_in,
                              void* d_out, int out_size, void* d_ws, size_t ws_size,
                              hipStream_t stream) {
  const float* x    = (const float*)d_in[0];
  const float* mask = (const float*)d_in[1];
  const float* W1   = (const float*)d_in[2];
  const float* W2   = (const float*)d_in[3];
  const float* W3   = (const float*)d_in[4];
  float* out = (float*)d_out;

  char* ws = (char*)d_ws;
  size_t off = 0;
  _Float16* xf   = (_Float16*)(ws + off); off += (size_t)4096 * 2048 * 2;    // 16 MiB
  _Float16* Wtf  = (_Float16*)(ws + off); off += (size_t)NFUSE * 2048 * 2;   //  9 MiB
  _Float16* QKf  = (_Float16*)(ws + off); off += (size_t)4096 * NFUSE * 2;   // 18 MiB
  _Float16* VT   = (_Float16*)(ws + off); off += (size_t)2 * 128 * 2048 * 2; //  1 MiB
  _Float16* AOf  = (_Float16*)(ws + off); off += (size_t)4096 * 2048 * 2;    // 16 MiB
  short*    maskb= (short*)(ws + off);    off += (size_t)2 * 2048 * 2048 * 2;// 16 MiB
  _Float16* W3t  = xf;  // alias: xf dead after fused GEMM; W3 transpose runs after

  // 1) prep: x->fp16 + mask->bf16*log2e (fused), W2^T fp16, W1-reduce+^T fp16
  cvt_xm_kernel<<<16384, 256, 0, stream>>>(x, xf, mask, maskb);
  transpose_f16_kernel<<<dim3(32, 32), 256, 0, stream>>>(W2, Wtf, 2048, 2048);
  transpose_wkv_kernel<<<dim3(4, 32), 256, 0, stream>>>(
      W1, Wtf + (size_t)2048 * 2048);

  // 2) fused projection GEMM: [4096][2304] = x @ [W2 | Wk | Wv], fp16 out,
  //    Q cols pre-scaled by log2e (grid 576 = 72/XCD, swizzled)
  gemm_f16<true><<<dim3(NFUSE / 128, 32), 256, 32768, stream>>>(
      xf, Wtf, nullptr, QKf, 4096, NFUSE, 2048, 2048);

  // 3) V^T extraction
  build_vt<<<64, 256, 0, stream>>>((const short*)QKf, (short*)VT);

  // 4) attention (R4 config: 512 blocks, 64 KiB LDS)
  flash_f16<<<dim3(S_LEN / 128, 2 * NHEAD), 256, 0, stream>>>(
      QKf, VT, maskb, AOf);

  // 5) output projection (fp16 in, f32 out; grid 512 = 64/XCD, swizzled)
  transpose_f16_kernel<<<dim3(32, 32), 256, 0, stream>>>(W3, W3t, 2048, 2048);
  gemm_f16<false><<<dim3(16, 32), 256, 32768, stream>>>(
      AOf, W3t, out, nullptr, 4096, 2048, 2048, 0);
}